// Round 5
// baseline (122.462 us; speedup 1.0000x reference)
//
#include <hip/hip_runtime.h>
#include <hip/hip_bf16.h>

// out[i][j] = (x@beta)[i][j] - 0.1*y[i][j]*||beta[:,j]||_1
//             + (4096*rowsum(W2)[j] + bias2[j] + bias_lin[j])
// M=4096, K=2048, N=1024. adv==1 always.
//
// Pipeline: memsetAsync(braw) -> pre_kernel (beta -> bf16 beta^T, stored
// PRE-SWIZZLED (xor chunk^(n&7) per 128B span) + column L1 atomics; W2 row
// sums) -> gemm_kernel (A=x fp32 via global_load_lds w/ pre-swizzled source,
// cvt to bf16 post-ds_read; B=bt via linear global_load_lds; 2-buf counted
// vmcnt(6); fused epilogue).

typedef float    f32x4  __attribute__((ext_vector_type(4)));
typedef unsigned u32x4  __attribute__((ext_vector_type(4)));
typedef short    bf16x8 __attribute__((ext_vector_type(8)));

constexpr int M = 4096;
constexpr int N = 1024;
constexpr int K = 2048;
constexpr int NHID = 4096;

constexpr int BM = 64, BN = 64, BK = 64;
constexpr int NT = K / BK;            // 32

__device__ __forceinline__ unsigned pkbf(float a, float b) {
    __hip_bfloat162 h = __float22bfloat162_rn(make_float2(a, b));
    unsigned u; __builtin_memcpy(&u, &h, 4); return u;
}

__device__ __forceinline__ void gll16(const void* g, void* l) {
    __builtin_amdgcn_global_load_lds(
        (const __attribute__((address_space(1))) void*)g,
        (__attribute__((address_space(3))) void*)l, 16, 0, 0);
}

// =================== pre: beta -> swizzled bf16 beta^T (+L1), W2 rowsums ====
// grid 768: [0,512) beta 64x64 tiles (tk = bx&31, tn = bx>>5); [512,768) W2.
__global__ void __launch_bounds__(256) pre_kernel(
    const float* __restrict__ beta, const float* __restrict__ W2,
    short* __restrict__ bt, float* __restrict__ braw,
    float* __restrict__ wsum) {
    __shared__ float tls[64 * 68];
    const int bx = blockIdx.x, tid = threadIdx.x;
    if (bx < 512) {
        const int tk = bx & 31, tn = bx >> 5;
        {   // phase 1: 64x64 fp32 tile of beta[k][n] -> LDS (row-major k)
            const int r = tid >> 2, c0 = (tid & 3) * 16;
            const float* src = beta + (size_t)(tk * 64 + r) * N + tn * 64 + c0;
            #pragma unroll
            for (int j = 0; j < 4; ++j)
                *(f32x4*)&tls[r * 68 + c0 + j * 4] = *(const f32x4*)(src + j * 4);
        }
        __syncthreads();
        {   // phase 2: transpose + cvt + L1; store chunks XOR-swizzled
            const int n = tid >> 2, k0 = (tid & 3) * 16;
            float s = 0.f;
            unsigned pk[8];
            #pragma unroll
            for (int j = 0; j < 8; ++j) {
                float a = tls[(k0 + 2 * j) * 68 + n];
                float b = tls[(k0 + 2 * j + 1) * 68 + n];
                s += fabsf(a) + fabsf(b);
                pk[j] = pkbf(a, b);
            }
            atomicAdd(&braw[tn * 64 + n], s);
            // row tn*64+n, k-span tk (64 k's = 8 chunks of 16B); our 2 chunks:
            // logical c = (tid&3)*2, c+1 -> slots c^(n&7)
            short* row = bt + (size_t)(tn * 64 + n) * K + tk * 64;
            const int c = (tid & 3) * 2, sw = n & 7;
            u32x4 p0 = { pk[0], pk[1], pk[2], pk[3] };
            u32x4 p1 = { pk[4], pk[5], pk[6], pk[7] };
            *(u32x4*)(row + (c ^ sw) * 8)       = p0;
            *(u32x4*)(row + ((c + 1) ^ sw) * 8) = p1;
        }
    } else {
        const int b = bx - 512;
        const int wv = tid >> 6, lane = tid & 63;
        const int row = b * 4 + wv;
        const f32x4* w4 = (const f32x4*)(W2 + (size_t)row * NHID);
        float acc = 0.f;
        #pragma unroll
        for (int i = 0; i < 16; ++i) {
            f32x4 v = w4[i * 64 + lane];
            acc += v[0] + v[1] + v[2] + v[3];
        }
        #pragma unroll
        for (int off = 32; off; off >>= 1) acc += __shfl_down(acc, off);
        if (lane == 0) wsum[row] = acc;
    }
}

// =================== main GEMM =============================================
// 64x64 tile, BK=64, 4 waves (2m x 2n), wave tile 32x32 (2x2 frags, 2 kk).
// A: fp32 in LDS (16KB/buf), staged by gll16 with XOR-preswizzled source.
// B: bf16 in LDS (8KB/buf), staged by gll16 linear (bt pre-swizzled in global).
// 2 buffers, counted vmcnt(6): tile t+1's 6 loads in flight across barriers.
__global__ void __launch_bounds__(256, 3) gemm_kernel(
    const float* __restrict__ x, const short* __restrict__ bt,
    const float* __restrict__ y,
    const float* __restrict__ braw, const float* __restrict__ wsum,
    const float* __restrict__ bias_lin, const float* __restrict__ bias2,
    float* __restrict__ out) {
    __shared__ __align__(16) float Alf[2][BM * BK];   // [row][chunk-slot] 16KB
    __shared__ __align__(16) short Bl[2][BN * BK];    // [row][chunk-slot]  8KB

    const int tid = threadIdx.x, lane = tid & 63, w = tid >> 6;
    const int wm = w >> 1, wn = w & 1;
    // XCD swizzle: xcd c: mb = ((c>>2)<<5) + local>>2 (32), nb = (c&3)*4 + local&3
    const int c = blockIdx.x & 7, local = blockIdx.x >> 3;
    const int mb = ((c >> 2) << 5) + (local >> 2);
    const int nb = ((c & 3) << 2) + (local & 3);
    const int brow = mb * BM, bcol = nb * BN;

    // ---- staging addresses ----
    // A inst i (0..3): rows w*16+i*4 .. +3; lane -> row +(lane>>4), slot lane&15.
    // fetch global chunk = slot ^ (row_local & 15)  (per-lane source swizzle)
    const float* asrc[4];
    int adst[4];
    #pragma unroll
    for (int i = 0; i < 4; ++i) {
        const int rl = i * 4 + (lane >> 4);           // row within wave's 16
        const int row_l = w * 16 + rl;
        const int chunk = (lane & 15) ^ (rl & 15);    // row_l&15 == rl&15
        asrc[i] = x + (size_t)(brow + row_l) * K + chunk * 4;
        adst[i] = (w * 16 + i * 4) * 64 + lane * 4;   // floats
    }
    // B inst i (0..1): rows w*16+i*8 .. +7; lane -> row +(lane>>3), slot lane&7.
    // bt already stored swizzled -> fetch linear.
    const short* bsrc[2];
    int bdst[2];
    #pragma unroll
    for (int i = 0; i < 2; ++i) {
        const int row_l = w * 16 + i * 8 + (lane >> 3);
        bsrc[i] = bt + (size_t)(bcol + row_l) * K + (lane & 7) * 8;
        bdst[i] = (w * 16 + i * 8) * 64 + lane * 8;   // shorts
    }

    auto STAGE = [&](int buf, int t) {
        #pragma unroll
        for (int i = 0; i < 4; ++i)
            gll16(asrc[i] + t * BK, &Alf[buf][adst[i]]);
        #pragma unroll
        for (int i = 0; i < 2; ++i)
            gll16(bsrc[i] + t * BK, &Bl[buf][bdst[i]]);
    };

    // ---- fragment LDS offsets (XOR-unswizzle on chunk index) ----
    const int r = lane & 15, q = lane >> 4;
    int aoff[2][2][2], boff[2][2];
    #pragma unroll
    for (int m = 0; m < 2; ++m)
        #pragma unroll
        for (int kk = 0; kk < 2; ++kk) {
            const int row = wm * 32 + m * 16 + r;     // row&15 == r
            const int c0 = kk * 8 + q * 2;
            aoff[m][kk][0] = row * 64 + ((c0    ) ^ r) * 4;
            aoff[m][kk][1] = row * 64 + ((c0 + 1) ^ r) * 4;
        }
    #pragma unroll
    for (int n = 0; n < 2; ++n)
        #pragma unroll
        for (int kk = 0; kk < 2; ++kk) {
            const int row = wn * 32 + n * 16 + r;     // row&7 == r&7
            const int cb = kk * 4 + q;
            boff[n][kk] = row * 64 + (cb ^ (r & 7)) * 8;
        }

    f32x4 acc[2][2];
    #pragma unroll
    for (int m = 0; m < 2; ++m)
        #pragma unroll
        for (int n = 0; n < 2; ++n) acc[m][n] = (f32x4)0.f;

    auto COMPUTE = [&](int buf) {
        #pragma unroll
        for (int kk = 0; kk < 2; ++kk) {
            bf16x8 af[2], bfr[2];
            #pragma unroll
            for (int m = 0; m < 2; ++m) {
                f32x4 lo = *(const f32x4*)&Alf[buf][aoff[m][kk][0]];
                f32x4 hi = *(const f32x4*)&Alf[buf][aoff[m][kk][1]];
                u32x4 p = { pkbf(lo[0], lo[1]), pkbf(lo[2], lo[3]),
                            pkbf(hi[0], hi[1]), pkbf(hi[2], hi[3]) };
                af[m] = *(bf16x8*)&p;
            }
            #pragma unroll
            for (int n = 0; n < 2; ++n)
                bfr[n] = *(const bf16x8*)&Bl[buf][boff[n][kk]];
            #pragma unroll
            for (int m = 0; m < 2; ++m)
                #pragma unroll
                for (int n = 0; n < 2; ++n)
                    acc[m][n] = __builtin_amdgcn_mfma_f32_16x16x32_bf16(
                        af[m], bfr[n], acc[m][n], 0, 0, 0);
        }
    };

    STAGE(0, 0);                                   // 6 loads outstanding
    for (int t = 0; t < NT; ++t) {
        const int buf = t & 1;
        // barrier 1: everyone done reading buf^1 (COMPUTE t-1)
        asm volatile("s_waitcnt lgkmcnt(0)" ::: "memory");
        __builtin_amdgcn_s_barrier();
        __builtin_amdgcn_sched_barrier(0);
        if (t + 1 < NT) {
            STAGE(buf ^ 1, t + 1);                 // outstanding: 6 old + 6 new
            asm volatile("s_waitcnt vmcnt(6)" ::: "memory");   // tile t landed
        } else {
            asm volatile("s_waitcnt vmcnt(0)" ::: "memory");
        }
        __builtin_amdgcn_sched_barrier(0);
        __builtin_amdgcn_s_barrier();              // barrier 2: tile t visible
        __builtin_amdgcn_sched_barrier(0);
        COMPUTE(buf);
    }

    // ---- epilogue: out = acc + cterm[col] - 0.1*braw[col]*y ----
    #pragma unroll
    for (int n = 0; n < 2; ++n) {
        const int gc = bcol + wn * 32 + n * 16 + r;
        const float be = 0.1f * braw[gc];
        const float ct = bias_lin[gc] + bias2[gc] + (float)NHID * wsum[gc];
        #pragma unroll
        for (int m = 0; m < 2; ++m) {
            const int gr0 = brow + wm * 32 + m * 16 + q * 4;
            f32x4 v = acc[m][n];
            #pragma unroll
            for (int rr = 0; rr < 4; ++rr) {
                size_t idx = (size_t)(gr0 + rr) * N + gc;
                out[idx] = v[rr] + ct - be * y[idx];
            }
        }
    }
}

extern "C" void kernel_launch(void* const* d_in, const int* in_sizes, int n_in,
                              void* d_out, int out_size, void* d_ws, size_t ws_size,
                              hipStream_t stream) {
    const float* x        = (const float*)d_in[0];
    const float* y        = (const float*)d_in[1];
    const float* beta     = (const float*)d_in[2];
    const float* bias_lin = (const float*)d_in[3];
    const float* W2       = (const float*)d_in[5];
    const float* bias2    = (const float*)d_in[7];
    float* out = (float*)d_out;

    float* braw = (float*)d_ws;                    // [1024]
    float* wsum = braw + 1024;                     // [1024]
    short* bts  = (short*)((char*)d_ws + 8192);    // [N][K] bf16, pre-swizzled

    hipMemsetAsync(braw, 0, 1024 * sizeof(float), stream);
    pre_kernel<<<768, 256, 0, stream>>>(beta, W2, bts, braw, wsum);
    gemm_kernel<<<1024, 256, 0, stream>>>(x, bts, y, braw, wsum,
                                          bias_lin, bias2, out);
}

// Round 6
// 109.760 us; speedup vs baseline: 1.1157x; 1.1157x over previous
//
#include <hip/hip_runtime.h>
#include <hip/hip_bf16.h>

// out[i][j] = (x@beta)[i][j] - 0.1*y[i][j]*||beta[:,j]||_1
//             + (4096*rowsum(W2)[j] + bias2[j] + bias_lin[j])
// M=4096, K=2048, N=1024. adv==1 always.
//
// Pipeline: memsetAsync(braw) -> pre_kernel (1792 blocks: x->bf16 streaming;
// beta -> bf16 beta^T + column-L1 atomics; W2 rowsums) -> gemm_kernel
// (round-4 structure: pure bf16, global_load_lds, 3-buf counted vmcnt(6),
// XOR-swizzled LDS via pre-swizzled per-lane SOURCE, fused epilogue).

typedef float    f32x4  __attribute__((ext_vector_type(4)));
typedef unsigned u32x2  __attribute__((ext_vector_type(2)));
typedef unsigned u32x4  __attribute__((ext_vector_type(4)));
typedef short    bf16x8 __attribute__((ext_vector_type(8)));

constexpr int M = 4096;
constexpr int N = 1024;
constexpr int K = 2048;
constexpr int NHID = 4096;

__device__ __forceinline__ unsigned pkbf(float a, float b) {
    __hip_bfloat162 h = __float22bfloat162_rn(make_float2(a, b));
    unsigned u; __builtin_memcpy(&u, &h, 4); return u;
}

__device__ __forceinline__ void gll16(const void* g, void* l) {
    __builtin_amdgcn_global_load_lds(
        (const __attribute__((address_space(1))) void*)g,
        (__attribute__((address_space(3))) void*)l, 16, 0, 0);
}

// =================== pre ====================================================
// grid 1792:
//   [0,1024)    : x -> xb bf16, 8 independent strided f32x4 per thread
//   [1024,1536) : beta 64x64 tiles -> bt[N][K] bf16 (LDS transpose) + L1 atomics
//   [1536,1792) : W2 row sums (4 rows/block, 1 per wave)
__global__ void __launch_bounds__(256) pre_kernel(
    const float* __restrict__ x, const float* __restrict__ beta,
    const float* __restrict__ W2,
    short* __restrict__ xb, short* __restrict__ bt,
    float* __restrict__ braw, float* __restrict__ wsum) {
    __shared__ float tls[64 * 68];
    const int bx = blockIdx.x, tid = threadIdx.x;
    if (bx < 1024) {
        const f32x4* x4 = (const f32x4*)x;
        u32x2* o2 = (u32x2*)xb;
        #pragma unroll
        for (int it = 0; it < 8; ++it) {
            const int i = (it * 1024 + bx) * 256 + tid;   // 2M f32x4 total
            f32x4 v = x4[i];
            u32x2 p = { pkbf(v[0], v[1]), pkbf(v[2], v[3]) };
            o2[i] = p;
        }
    } else if (bx < 1536) {
        const int tile = bx - 1024, tk = tile & 31, tn = tile >> 5;
        {   // phase 1: 64x64 fp32 tile of beta[k][n] -> LDS
            const int r = tid >> 2, c0 = (tid & 3) * 16;
            const float* src = beta + (size_t)(tk * 64 + r) * N + tn * 64 + c0;
            #pragma unroll
            for (int j = 0; j < 4; ++j)
                *(f32x4*)&tls[r * 68 + c0 + j * 4] = *(const f32x4*)(src + j * 4);
        }
        __syncthreads();
        {   // phase 2: transpose + cvt + column L1
            const int n = tid >> 2, k0 = (tid & 3) * 16;
            float s = 0.f;
            unsigned pk[8];
            #pragma unroll
            for (int j = 0; j < 8; ++j) {
                float a = tls[(k0 + 2 * j) * 68 + n];
                float b = tls[(k0 + 2 * j + 1) * 68 + n];
                s += fabsf(a) + fabsf(b);
                pk[j] = pkbf(a, b);
            }
            atomicAdd(&braw[tn * 64 + n], s);
            u32x4* dst = (u32x4*)(bt + (size_t)(tn * 64 + n) * K + tk * 64 + k0);
            u32x4 p0 = { pk[0], pk[1], pk[2], pk[3] };
            u32x4 p1 = { pk[4], pk[5], pk[6], pk[7] };
            dst[0] = p0; dst[1] = p1;
        }
    } else {
        const int b = bx - 1536;
        const int wv = tid >> 6, lane = tid & 63;
        const int row = b * 4 + wv;
        const f32x4* w4 = (const f32x4*)(W2 + (size_t)row * NHID);
        float acc = 0.f;
        #pragma unroll
        for (int i = 0; i < 16; ++i) {
            f32x4 v = w4[i * 64 + lane];
            acc += v[0] + v[1] + v[2] + v[3];
        }
        #pragma unroll
        for (int off = 32; off; off >>= 1) acc += __shfl_down(acc, off);
        if (lane == 0) wsum[row] = acc;
    }
}

// =================== main GEMM: bf16, global_load_lds, 3-buf vmcnt(6) =======
// BM=128 x BN=64, BK=64, 4 waves (2m x 2n), wave tile 64x32 (4x2 frags, 2 kk).
// Grid 512 -> 2 blocks/CU. LDS 72KB (3 buffers). One barrier per K-step.
// XOR swizzle: LDS slot (row, c) holds global chunk c^(row&7); reads XOR back.
constexpr int BM = 128, BN = 64, BK = 64;
constexpr int NT  = K / BK;          // 32
constexpr int ASZ = BM * BK;         // 8192 shorts (16KB)
constexpr int BSZ = BN * BK;         // 4096 shorts (8KB)

__global__ void __launch_bounds__(256, 2) gemm_kernel(
    const short* __restrict__ xb, const short* __restrict__ bt,
    const float* __restrict__ y,
    const float* __restrict__ braw, const float* __restrict__ wsum,
    const float* __restrict__ bias_lin, const float* __restrict__ bias2,
    float* __restrict__ out) {
    __shared__ __align__(16) short Al[3 * ASZ];
    __shared__ __align__(16) short Bl[3 * BSZ];

    const int tid = threadIdx.x, lane = tid & 63, w = tid >> 6;
    const int wm = w >> 1, wn = w & 1;
    // XCD swizzle: xcd c gets 16mb x 4nb contiguous region (512 = 8 x 64)
    const int c = blockIdx.x & 7, local = blockIdx.x >> 3;
    const int mb = ((c & 1) << 4) + (local >> 2);
    const int nb = ((c >> 1) << 2) + (local & 3);
    const int brow = mb * BM, bcol = nb * BN;

    // staging: per-lane pre-swizzled global source, linear LDS dest
    const int srow = lane >> 3;                 // 0..7 within 8-row stripe
    const int schk = (lane & 7) ^ srow;         // fetch chunk for slot (srow, lane&7)
    const short* asrc = xb + (size_t)(brow + w * 32 + srow) * K + schk * 8;
    const short* bsrc = bt + (size_t)(bcol + w * 16 + srow) * K + schk * 8;
    short* Abase = &Al[w * 2048];
    short* Bbase = &Bl[w * 1024];

    f32x4 acc[4][2];
    #pragma unroll
    for (int m = 0; m < 4; ++m)
        #pragma unroll
        for (int n = 0; n < 2; ++n) acc[m][n] = (f32x4)0.f;

    auto STAGE = [&](int buf, int t) {
        const short* a = asrc + t * BK;
        #pragma unroll
        for (int i = 0; i < 4; ++i)
            gll16(a + (size_t)i * 8 * K, Abase + buf * ASZ + i * 512);
        const short* b = bsrc + t * BK;
        #pragma unroll
        for (int i = 0; i < 2; ++i)
            gll16(b + (size_t)i * 8 * K, Bbase + buf * BSZ + i * 512);
    };

    // fragment LDS offsets (shorts), with XOR-unswizzle on the chunk index
    const int r = lane & 15, q = lane >> 4;
    int aoff[4][2], boff[2][2];
    #pragma unroll
    for (int m = 0; m < 4; ++m)
        #pragma unroll
        for (int kk = 0; kk < 2; ++kk) {
            int row = wm * 64 + m * 16 + r;
            int ch = (kk * 4 + q) ^ (r & 7);
            aoff[m][kk] = row * 64 + ch * 8;
        }
    #pragma unroll
    for (int n = 0; n < 2; ++n)
        #pragma unroll
        for (int kk = 0; kk < 2; ++kk) {
            int row = wn * 32 + n * 16 + r;
            int ch = (kk * 4 + q) ^ (r & 7);
            boff[n][kk] = row * 64 + ch * 8;
        }

    auto COMPUTE = [&](int buf) {
        const short* A = &Al[buf * ASZ];
        const short* B = &Bl[buf * BSZ];
        #pragma unroll
        for (int kk = 0; kk < 2; ++kk) {
            bf16x8 af[4], bfr[2];
            #pragma unroll
            for (int m = 0; m < 4; ++m) af[m] = *(const bf16x8*)&A[aoff[m][kk]];
            #pragma unroll
            for (int n = 0; n < 2; ++n) bfr[n] = *(const bf16x8*)&B[boff[n][kk]];
            #pragma unroll
            for (int m = 0; m < 4; ++m)
                #pragma unroll
                for (int n = 0; n < 2; ++n)
                    acc[m][n] = __builtin_amdgcn_mfma_f32_16x16x32_bf16(
                        af[m], bfr[n], acc[m][n], 0, 0, 0);
        }
    };

    STAGE(0, 0);
    STAGE(1, 1);
    for (int t = 0; t < NT; ++t) {
        if (t < NT - 1) { asm volatile("s_waitcnt vmcnt(6)" ::: "memory"); }
        else            { asm volatile("s_waitcnt vmcnt(0)" ::: "memory"); }
        __builtin_amdgcn_s_barrier();
        __builtin_amdgcn_sched_barrier(0);
        if (t + 2 < NT) STAGE((t + 2) % 3, t + 2);
        COMPUTE(t % 3);
    }

    // epilogue: out = acc + cterm[col] - 0.1*braw[col]*y
    #pragma unroll
    for (int n = 0; n < 2; ++n) {
        const int gc = bcol + wn * 32 + n * 16 + r;
        const float be = 0.1f * braw[gc];
        const float ct = bias_lin[gc] + bias2[gc] + (float)NHID * wsum[gc];
        #pragma unroll
        for (int m = 0; m < 4; ++m) {
            const int gr0 = brow + wm * 64 + m * 16 + q * 4;
            f32x4 v = acc[m][n];
            #pragma unroll
            for (int rr = 0; rr < 4; ++rr) {
                size_t idx = (size_t)(gr0 + rr) * N + gc;
                out[idx] = v[rr] + ct - be * y[idx];
            }
        }
    }
}

extern "C" void kernel_launch(void* const* d_in, const int* in_sizes, int n_in,
                              void* d_out, int out_size, void* d_ws, size_t ws_size,
                              hipStream_t stream) {
    const float* x        = (const float*)d_in[0];
    const float* y        = (const float*)d_in[1];
    const float* beta     = (const float*)d_in[2];
    const float* bias_lin = (const float*)d_in[3];
    const float* W2       = (const float*)d_in[5];
    const float* bias2    = (const float*)d_in[7];
    float* out = (float*)d_out;

    float* braw = (float*)d_ws;                    // [1024]
    float* wsum = braw + 1024;                     // [1024]
    short* xb   = (short*)((char*)d_ws + 8192);    // [M][K] bf16
    short* bts  = xb + (size_t)M * K;              // [N][K] bf16 (beta^T)

    hipMemsetAsync(braw, 0, 1024 * sizeof(float), stream);
    pre_kernel<<<1792, 256, 0, stream>>>(x, beta, W2, xb, bts, braw, wsum);
    gemm_kernel<<<512, 256, 0, stream>>>(xb, bts, y, braw, wsum,
                                         bias_lin, bias2, out);
}

// Round 7
// 70.642 us; speedup vs baseline: 1.7336x; 1.5538x over previous
//
#include <hip/hip_runtime.h>
#include <hip/hip_bf16.h>

// out[i][j] = (x@beta)[i][j] - 0.1*y[i][j]*||beta[:,j]||_1
//             + (4096*rowsum(W2)[j] + bias2[j] + bias_lin[j])
// M=4096, K=2048, N=1024. adv==1 always.
//
// Pipeline: pre_kernel (beta -> bf16 beta^T linear + column-L1 partials via
// shfl (NO atomics); W2 rowsums) -> gemm_kernel (A = x f32 via global_load_lds
// with per-lane source swizzle, cvt to bf16 after ds_read; B = bt bf16 via
// gll16 with source swizzle; 3-buf, lookahead-2, counted vmcnt(5); epilogue
// sums L1 partials + fuses the adv terms).

typedef float    f32x4  __attribute__((ext_vector_type(4)));
typedef unsigned u32x4  __attribute__((ext_vector_type(4)));
typedef short    bf16x8 __attribute__((ext_vector_type(8)));

constexpr int M = 4096;
constexpr int N = 1024;
constexpr int K = 2048;
constexpr int NHID = 4096;

__device__ __forceinline__ unsigned pkbf(float a, float b) {
    __hip_bfloat162 h = __float22bfloat162_rn(make_float2(a, b));
    unsigned u; __builtin_memcpy(&u, &h, 4); return u;
}

__device__ __forceinline__ void gll16(const void* g, void* l) {
    __builtin_amdgcn_global_load_lds(
        (const __attribute__((address_space(1))) void*)g,
        (__attribute__((address_space(3))) void*)l, 16, 0, 0);
}

// =================== pre ====================================================
// grid 768: [0,512) beta 64x64 tiles -> bt[N][K] bf16 + L1 partials (shfl);
//           [512,768) W2 row sums (4 rows/block, 1 per wave).
__global__ void __launch_bounds__(256) pre_kernel(
    const float* __restrict__ beta, const float* __restrict__ W2,
    short* __restrict__ bt, float* __restrict__ partials,  // [32][1024]
    float* __restrict__ wsum) {
    __shared__ float tls[64 * 68];
    const int bx = blockIdx.x, tid = threadIdx.x;
    if (bx < 512) {
        const int tk = bx & 31, tn = bx >> 5;
        {   // phase 1: 64x64 fp32 tile of beta[k][n] -> LDS
            const int r = tid >> 2, c0 = (tid & 3) * 16;
            const float* src = beta + (size_t)(tk * 64 + r) * N + tn * 64 + c0;
            #pragma unroll
            for (int j = 0; j < 4; ++j)
                *(f32x4*)&tls[r * 68 + c0 + j * 4] = *(const f32x4*)(src + j * 4);
        }
        __syncthreads();
        {   // phase 2: transpose + cvt + column-L1 (4-lane shfl reduce)
            const int n = tid >> 2, k0 = (tid & 3) * 16;
            float s = 0.f;
            unsigned pk[8];
            #pragma unroll
            for (int j = 0; j < 8; ++j) {
                float a = tls[(k0 + 2 * j) * 68 + n];
                float b = tls[(k0 + 2 * j + 1) * 68 + n];
                s += fabsf(a) + fabsf(b);
                pk[j] = pkbf(a, b);
            }
            s += __shfl_xor(s, 1);
            s += __shfl_xor(s, 2);
            if ((tid & 3) == 0) partials[tk * 1024 + tn * 64 + n] = s;
            u32x4* dst = (u32x4*)(bt + (size_t)(tn * 64 + n) * K + tk * 64 + k0);
            u32x4 p0 = { pk[0], pk[1], pk[2], pk[3] };
            u32x4 p1 = { pk[4], pk[5], pk[6], pk[7] };
            dst[0] = p0; dst[1] = p1;
        }
    } else {
        const int b = bx - 512;
        const int wv = tid >> 6, lane = tid & 63;
        const int row = b * 4 + wv;
        const f32x4* w4 = (const f32x4*)(W2 + (size_t)row * NHID);
        float acc = 0.f;
        #pragma unroll
        for (int i = 0; i < 16; ++i) {
            f32x4 v = w4[i * 64 + lane];
            acc += v[0] + v[1] + v[2] + v[3];
        }
        #pragma unroll
        for (int off = 32; off; off >>= 1) acc += __shfl_down(acc, off);
        if (lane == 0) wsum[row] = acc;
    }
}

// =================== main GEMM ==============================================
// BM=128 x BN=64, BK=32, 4 waves (2m x 2n), wave tile 64x32 (4x2 frags).
// A: f32 in LDS [row][8 slots x 16B], slot_phys = chunk ^ (row&7).
// B: bf16 in LDS [row][4 slots x 16B], slot_phys = chunk ^ ((row>>1)&3).
// Both staged by global_load_lds with the inverse swizzle on the per-lane
// GLOBAL source (linear LDS dest). 3 buffers, lookahead-2, vmcnt(5).
constexpr int BM = 128, BN = 64, BK = 32;
constexpr int NT = K / BK;           // 64

__global__ void __launch_bounds__(256, 2) gemm_kernel(
    const float* __restrict__ x, const short* __restrict__ bt,
    const float* __restrict__ y,
    const float* __restrict__ partials, const float* __restrict__ wsum,
    const float* __restrict__ bias_lin, const float* __restrict__ bias2,
    float* __restrict__ out) {
    __shared__ __align__(16) float Af[3][BM * BK];   // 16KB each
    __shared__ __align__(16) short Bl[3][BN * BK];   //  4KB each

    const int tid = threadIdx.x, lane = tid & 63, w = tid >> 6;
    const int wm = w >> 1, wn = w & 1;
    // XCD swizzle: 512 = 8 chunks x 64; chunk: 16mb x 4nb
    const int c = blockIdx.x & 7, local = blockIdx.x >> 3;
    const int mb = ((c & 1) << 4) + (local >> 2);
    const int nb = ((c >> 1) << 2) + (local & 3);
    const int brow = mb * BM, bcol = nb * BN;

    // ---- staging addresses (per-lane source swizzle, linear LDS dest) ----
    // A: 4 insts; inst i covers rows i*32 + w*8 + (lane>>3), slot = lane&7
    const int arow_off = lane >> 3, aslot = lane & 7;
    const float* asrc[4];
    int adst[4];                                   // float index
    #pragma unroll
    for (int i = 0; i < 4; ++i) {
        const int row_l = i * 32 + w * 8 + arow_off;      // row_l & 7 == arow_off
        const int chunk = aslot ^ arow_off;
        asrc[i] = x + (size_t)(brow + row_l) * K + chunk * 4;
        adst[i] = row_l * BK + aslot * 4;
    }
    // B: 1 inst; rows w*16 + (lane>>2), slot = lane&3
    const int brow_off = lane >> 2, bslot = lane & 3;
    const int bchunk = bslot ^ ((brow_off >> 1) & 3);
    const short* bsrc = bt + (size_t)(bcol + w * 16 + brow_off) * K + bchunk * 8;
    const int bdst = (w * 16 + brow_off) * BK + bslot * 8;  // short index

    auto STAGE = [&](int buf, int t) {
        #pragma unroll
        for (int i = 0; i < 4; ++i)
            gll16(asrc[i] + t * BK, &Af[buf][adst[i]]);
        gll16(bsrc + t * BK, &Bl[buf][bdst]);
    };

    // ---- fragment read offsets (apply the same XOR) ----
    const int r = lane & 15, q = lane >> 4;
    int aoff[4][2], boff[2];
    #pragma unroll
    for (int m = 0; m < 4; ++m)
        #pragma unroll
        for (int e = 0; e < 2; ++e) {
            const int row = wm * 64 + m * 16 + r;          // row&7 == r&7
            aoff[m][e] = row * BK + (((q * 2 + e) ^ (r & 7)) * 4);
        }
    #pragma unroll
    for (int n = 0; n < 2; ++n) {
        const int row = wn * 32 + n * 16 + r;              // (row>>1)&3 == (r>>1)&3
        boff[n] = row * BK + ((q ^ ((r >> 1) & 3)) * 8);
    }

    f32x4 acc[4][2];
    #pragma unroll
    for (int m = 0; m < 4; ++m)
        #pragma unroll
        for (int n = 0; n < 2; ++n) acc[m][n] = (f32x4)0.f;

    auto COMPUTE = [&](int buf) {
        bf16x8 af[4], bfr[2];
        #pragma unroll
        for (int m = 0; m < 4; ++m) {
            f32x4 lo = *(const f32x4*)&Af[buf][aoff[m][0]];
            f32x4 hi = *(const f32x4*)&Af[buf][aoff[m][1]];
            u32x4 p = { pkbf(lo[0], lo[1]), pkbf(lo[2], lo[3]),
                        pkbf(hi[0], hi[1]), pkbf(hi[2], hi[3]) };
            af[m] = *(bf16x8*)&p;
        }
        #pragma unroll
        for (int n = 0; n < 2; ++n)
            bfr[n] = *(const bf16x8*)&Bl[buf][boff[n]];
        #pragma unroll
        for (int m = 0; m < 4; ++m)
            #pragma unroll
            for (int n = 0; n < 2; ++n)
                acc[m][n] = __builtin_amdgcn_mfma_f32_16x16x32_bf16(
                    af[m], bfr[n], acc[m][n], 0, 0, 0);
    };

    STAGE(0, 0);
    STAGE(1, 1);
    for (int t = 0; t < NT; ++t) {
        if (t < NT - 1) { asm volatile("s_waitcnt vmcnt(5)" ::: "memory"); }
        else            { asm volatile("s_waitcnt vmcnt(0)" ::: "memory"); }
        __builtin_amdgcn_s_barrier();
        __builtin_amdgcn_sched_barrier(0);
        if (t + 2 < NT) STAGE((t + 2) % 3, t + 2);
        COMPUTE(t % 3);
    }

    // ---- epilogue: out = acc + cterm[col] - 0.1*bnorm[col]*y ----
    #pragma unroll
    for (int n = 0; n < 2; ++n) {
        const int gc = bcol + wn * 32 + n * 16 + r;
        float bsum = 0.f;
        #pragma unroll 8
        for (int tk = 0; tk < 32; ++tk) bsum += partials[tk * 1024 + gc];
        const float be = 0.1f * bsum;
        const float ct = bias_lin[gc] + bias2[gc] + (float)NHID * wsum[gc];
        #pragma unroll
        for (int m = 0; m < 4; ++m) {
            const int gr0 = brow + wm * 64 + m * 16 + q * 4;
            f32x4 v = acc[m][n];
            #pragma unroll
            for (int rr = 0; rr < 4; ++rr) {
                size_t idx = (size_t)(gr0 + rr) * N + gc;
                out[idx] = v[rr] + ct - be * y[idx];
            }
        }
    }
}

extern "C" void kernel_launch(void* const* d_in, const int* in_sizes, int n_in,
                              void* d_out, int out_size, void* d_ws, size_t ws_size,
                              hipStream_t stream) {
    const float* x        = (const float*)d_in[0];
    const float* y        = (const float*)d_in[1];
    const float* beta     = (const float*)d_in[2];
    const float* bias_lin = (const float*)d_in[3];
    const float* W2       = (const float*)d_in[5];
    const float* bias2    = (const float*)d_in[7];
    float* out = (float*)d_out;

    float* partials = (float*)d_ws;                        // [32][1024]
    float* wsum     = partials + 32 * 1024;                // [1024]
    short* bts      = (short*)(wsum + 1024);               // [N][K] bf16 (beta^T)

    pre_kernel<<<768, 256, 0, stream>>>(beta, W2, bts, partials, wsum);
    gemm_kernel<<<512, 256, 0, stream>>>(x, bts, y, partials, wsum,
                                         bias_lin, bias2, out);
}

// Round 8
// 61.123 us; speedup vs baseline: 2.0035x; 1.1557x over previous
//
#include <hip/hip_runtime.h>
#include <hip/hip_bf16.h>

// out[i][j] = (x@beta)[i][j] - 0.1*y[i][j]*||beta[:,j]||_1
//             + (4096*rowsum(W2)[j] + bias2[j] + bias_lin[j])
// M=4096, K=2048, N=1024. adv==1 always.
//
// Pipeline (all atomic-free):
//   pre_kernel  grid 1792: [0,1024) x->bf16 streaming; [1024,1536) beta 64x64
//               tiles -> bt[N][K] bf16 (beta^T) + column-L1 partials via shfl;
//               [1536,1792) W2 row sums.
//   gemm_kernel grid 512: pure-bf16 MFMA, BM=128 BN=64 BK=64, 3 LDS buffers,
//               lookahead-2 global_load_lds with counted vmcnt(6), XOR-swizzled
//               128B-row LDS (zero-conflict pattern verified round 5), fused
//               epilogue (sums L1 partials, adds cterm, subtracts eps*y*L1).

typedef float    f32x4  __attribute__((ext_vector_type(4)));
typedef unsigned u32x2  __attribute__((ext_vector_type(2)));
typedef unsigned u32x4  __attribute__((ext_vector_type(4)));
typedef short    bf16x8 __attribute__((ext_vector_type(8)));

constexpr int M = 4096;
constexpr int N = 1024;
constexpr int K = 2048;
constexpr int NHID = 4096;

__device__ __forceinline__ unsigned pkbf(float a, float b) {
    __hip_bfloat162 h = __float22bfloat162_rn(make_float2(a, b));
    unsigned u; __builtin_memcpy(&u, &h, 4); return u;
}

__device__ __forceinline__ void gll16(const void* g, void* l) {
    __builtin_amdgcn_global_load_lds(
        (const __attribute__((address_space(1))) void*)g,
        (__attribute__((address_space(3))) void*)l, 16, 0, 0);
}

// =================== pre ====================================================
__global__ void __launch_bounds__(256) pre_kernel(
    const float* __restrict__ x, const float* __restrict__ beta,
    const float* __restrict__ W2,
    short* __restrict__ xb, short* __restrict__ bt,
    float* __restrict__ partials,   // [32][1024]
    float* __restrict__ wsum) {     // [1024]
    __shared__ float tls[64 * 68];
    const int bx = blockIdx.x, tid = threadIdx.x;
    if (bx < 1024) {
        // ---- x -> bf16: 2M f32x4, 1024 blocks x 256 threads x 8 iters ----
        const f32x4* x4 = (const f32x4*)x;
        u32x2* o2 = (u32x2*)xb;
        #pragma unroll
        for (int it = 0; it < 8; ++it) {
            const int i = (it * 1024 + bx) * 256 + tid;
            f32x4 v = x4[i];
            u32x2 p = { pkbf(v[0], v[1]), pkbf(v[2], v[3]) };
            o2[i] = p;
        }
    } else if (bx < 1536) {
        // ---- beta 64x64 tile: transpose + cvt + L1 partials (shfl) ----
        const int tile = bx - 1024, tk = tile & 31, tn = tile >> 5;
        {   // phase 1: 64x64 fp32 tile of beta[k][n] -> LDS
            const int r = tid >> 2, c0 = (tid & 3) * 16;
            const float* src = beta + (size_t)(tk * 64 + r) * N + tn * 64 + c0;
            #pragma unroll
            for (int j = 0; j < 4; ++j)
                *(f32x4*)&tls[r * 68 + c0 + j * 4] = *(const f32x4*)(src + j * 4);
        }
        __syncthreads();
        {   // phase 2: transpose + cvt + column-L1 (4-lane shfl reduce)
            const int n = tid >> 2, k0 = (tid & 3) * 16;
            float s = 0.f;
            unsigned pk[8];
            #pragma unroll
            for (int j = 0; j < 8; ++j) {
                float a = tls[(k0 + 2 * j) * 68 + n];
                float b = tls[(k0 + 2 * j + 1) * 68 + n];
                s += fabsf(a) + fabsf(b);
                pk[j] = pkbf(a, b);
            }
            s += __shfl_xor(s, 1);
            s += __shfl_xor(s, 2);
            if ((tid & 3) == 0) partials[tk * 1024 + tn * 64 + n] = s;
            u32x4* dst = (u32x4*)(bt + (size_t)(tn * 64 + n) * K + tk * 64 + k0);
            u32x4 p0 = { pk[0], pk[1], pk[2], pk[3] };
            u32x4 p1 = { pk[4], pk[5], pk[6], pk[7] };
            dst[0] = p0; dst[1] = p1;
        }
    } else {
        // ---- W2 row sums: 256 blocks, 4 rows/block (1 per wave) ----
        const int b = bx - 1536;
        const int wv = tid >> 6, lane = tid & 63;
        const int row = b * 4 + wv;
        const f32x4* w4 = (const f32x4*)(W2 + (size_t)row * NHID);
        float acc = 0.f;
        #pragma unroll
        for (int i = 0; i < 16; ++i) {
            f32x4 v = w4[i * 64 + lane];
            acc += v[0] + v[1] + v[2] + v[3];
        }
        #pragma unroll
        for (int off = 32; off; off >>= 1) acc += __shfl_down(acc, off);
        if (lane == 0) wsum[row] = acc;
    }
}

// =================== main GEMM: bf16, global_load_lds, 3-buf vmcnt(6) =======
// BM=128 x BN=64, BK=64, 4 waves (2m x 2n), wave tile 64x32 (4x2 frags, 2 kk).
// Grid 512 -> 2 blocks/CU. LDS 72KB (3 buffers). One barrier per K-step.
// XOR swizzle: LDS slot (row, s) holds global chunk s^(row&7); reads XOR back.
// 128B row stride + 3-bit XOR = the zero-conflict pattern (round-5 measured).
constexpr int BM = 128, BN = 64, BK = 64;
constexpr int NT  = K / BK;          // 32
constexpr int ASZ = BM * BK;         // 8192 shorts (16KB)
constexpr int BSZ = BN * BK;         // 4096 shorts (8KB)

__global__ void __launch_bounds__(256, 2) gemm_kernel(
    const short* __restrict__ xb, const short* __restrict__ bt,
    const float* __restrict__ y,
    const float* __restrict__ partials, const float* __restrict__ wsum,
    const float* __restrict__ bias_lin, const float* __restrict__ bias2,
    float* __restrict__ out) {
    __shared__ __align__(16) short Al[3 * ASZ];
    __shared__ __align__(16) short Bl[3 * BSZ];

    const int tid = threadIdx.x, lane = tid & 63, w = tid >> 6;
    const int wm = w >> 1, wn = w & 1;
    // XCD swizzle: xcd c gets 16mb x 4nb contiguous region (512 = 8 x 64)
    const int c = blockIdx.x & 7, local = blockIdx.x >> 3;
    const int mb = ((c & 1) << 4) + (local >> 2);
    const int nb = ((c >> 1) << 2) + (local & 3);
    const int brow = mb * BM, bcol = nb * BN;

    // staging: per-lane pre-swizzled global source, linear LDS dest
    const int srow = lane >> 3;                 // 0..7 within 8-row stripe
    const int schk = (lane & 7) ^ srow;         // fetch chunk for slot (srow, lane&7)
    const short* asrc = xb + (size_t)(brow + w * 32 + srow) * K + schk * 8;
    const short* bsrc = bt + (size_t)(bcol + w * 16 + srow) * K + schk * 8;
    short* Abase = &Al[w * 2048];
    short* Bbase = &Bl[w * 1024];

    f32x4 acc[4][2];
    #pragma unroll
    for (int m = 0; m < 4; ++m)
        #pragma unroll
        for (int n = 0; n < 2; ++n) acc[m][n] = (f32x4)0.f;

    auto STAGE = [&](int buf, int t) {
        const short* a = asrc + t * BK;
        #pragma unroll
        for (int i = 0; i < 4; ++i)
            gll16(a + (size_t)i * 8 * K, Abase + buf * ASZ + i * 512);
        const short* b = bsrc + t * BK;
        #pragma unroll
        for (int i = 0; i < 2; ++i)
            gll16(b + (size_t)i * 8 * K, Bbase + buf * BSZ + i * 512);
    };

    // fragment LDS offsets (shorts), with XOR-unswizzle on the chunk index
    const int r = lane & 15, q = lane >> 4;
    int aoff[4][2], boff[2][2];
    #pragma unroll
    for (int m = 0; m < 4; ++m)
        #pragma unroll
        for (int kk = 0; kk < 2; ++kk) {
            int row = wm * 64 + m * 16 + r;
            int ch = (kk * 4 + q) ^ (r & 7);
            aoff[m][kk] = row * 64 + ch * 8;
        }
    #pragma unroll
    for (int n = 0; n < 2; ++n)
        #pragma unroll
        for (int kk = 0; kk < 2; ++kk) {
            int row = wn * 32 + n * 16 + r;
            int ch = (kk * 4 + q) ^ (r & 7);
            boff[n][kk] = row * 64 + ch * 8;
        }

    auto COMPUTE = [&](int buf) {
        const short* A = &Al[buf * ASZ];
        const short* B = &Bl[buf * BSZ];
        #pragma unroll
        for (int kk = 0; kk < 2; ++kk) {
            bf16x8 af[4], bfr[2];
            #pragma unroll
            for (int m = 0; m < 4; ++m) af[m] = *(const bf16x8*)&A[aoff[m][kk]];
            #pragma unroll
            for (int n = 0; n < 2; ++n) bfr[n] = *(const bf16x8*)&B[boff[n][kk]];
            #pragma unroll
            for (int m = 0; m < 4; ++m)
                #pragma unroll
                for (int n = 0; n < 2; ++n)
                    acc[m][n] = __builtin_amdgcn_mfma_f32_16x16x32_bf16(
                        af[m], bfr[n], acc[m][n], 0, 0, 0);
        }
    };

    STAGE(0, 0);
    STAGE(1, 1);
    for (int t = 0; t < NT; ++t) {
        if (t < NT - 1) { asm volatile("s_waitcnt vmcnt(6)" ::: "memory"); }
        else            { asm volatile("s_waitcnt vmcnt(0)" ::: "memory"); }
        __builtin_amdgcn_s_barrier();
        __builtin_amdgcn_sched_barrier(0);
        if (t + 2 < NT) STAGE((t + 2) % 3, t + 2);
        COMPUTE(t % 3);
    }

    // epilogue: out = acc + cterm[col] - 0.1*bnorm[col]*y
    #pragma unroll
    for (int n = 0; n < 2; ++n) {
        const int gc = bcol + wn * 32 + n * 16 + r;
        float bsum = 0.f;
        #pragma unroll 8
        for (int tk = 0; tk < 32; ++tk) bsum += partials[tk * 1024 + gc];
        const float be = 0.1f * bsum;
        const float ct = bias_lin[gc] + bias2[gc] + (float)NHID * wsum[gc];
        #pragma unroll
        for (int m = 0; m < 4; ++m) {
            const int gr0 = brow + wm * 64 + m * 16 + q * 4;
            f32x4 v = acc[m][n];
            #pragma unroll
            for (int rr = 0; rr < 4; ++rr) {
                size_t idx = (size_t)(gr0 + rr) * N + gc;
                out[idx] = v[rr] + ct - be * y[idx];
            }
        }
    }
}

extern "C" void kernel_launch(void* const* d_in, const int* in_sizes, int n_in,
                              void* d_out, int out_size, void* d_ws, size_t ws_size,
                              hipStream_t stream) {
    const float* x        = (const float*)d_in[0];
    const float* y        = (const float*)d_in[1];
    const float* beta     = (const float*)d_in[2];
    const float* bias_lin = (const float*)d_in[3];
    const float* W2       = (const float*)d_in[5];
    const float* bias2    = (const float*)d_in[7];
    float* out = (float*)d_out;

    float* partials = (float*)d_ws;                        // [32][1024]
    float* wsum     = partials + 32 * 1024;                // [1024]
    short* xb       = (short*)(wsum + 1024);               // [M][K] bf16
    short* bts      = xb + (size_t)M * K;                  // [N][K] bf16 (beta^T)

    pre_kernel<<<1792, 256, 0, stream>>>(x, beta, W2, xb, bts, partials, wsum);
    gemm_kernel<<<512, 256, 0, stream>>>(xb, bts, y, partials, wsum,
                                         bias_lin, bias2, out);
}

// Round 9
// 50.292 us; speedup vs baseline: 2.4350x; 1.2154x over previous
//
#include <hip/hip_runtime.h>
#include <hip/hip_bf16.h>

// out[i][j] = (x@beta)[i][j] - 0.1*y[i][j]*||beta[:,j]||_1
//             + (4096*rowsum(W2)[j] + bias2[j] + bias_lin[j])
// M=4096, K=2048, N=1024. adv==1 always.
//
// Pipeline (all atomic-free):
//   pre_kernel  grid 1792: [0,1024) x->bf16 streaming; [1024,1536) beta 64x64
//               tiles -> bt[N][K] bf16 (beta^T) + column-L1 partials via shfl;
//               [1536,1792) W2 row sums.   (~at HBM roofline, round-8 measured)
//   gemm_kernel grid 512 x 512 threads (8 waves, 4m x 2n wave grid, 32x32
//               wave tiles): pure-bf16 MFMA, BM=128 BN=64 BK=64, 3 LDS bufs,
//               lookahead-2 global_load_lds, counted vmcnt(3), XOR-swizzled
//               128B-row LDS (zero-conflict, round-8 measured), fused epilogue.

typedef float    f32x4  __attribute__((ext_vector_type(4)));
typedef unsigned u32x2  __attribute__((ext_vector_type(2)));
typedef unsigned u32x4  __attribute__((ext_vector_type(4)));
typedef short    bf16x8 __attribute__((ext_vector_type(8)));

constexpr int M = 4096;
constexpr int N = 1024;
constexpr int K = 2048;
constexpr int NHID = 4096;

__device__ __forceinline__ unsigned pkbf(float a, float b) {
    __hip_bfloat162 h = __float22bfloat162_rn(make_float2(a, b));
    unsigned u; __builtin_memcpy(&u, &h, 4); return u;
}

__device__ __forceinline__ void gll16(const void* g, void* l) {
    __builtin_amdgcn_global_load_lds(
        (const __attribute__((address_space(1))) void*)g,
        (__attribute__((address_space(3))) void*)l, 16, 0, 0);
}

// =================== pre (unchanged from round 8) ===========================
__global__ void __launch_bounds__(256) pre_kernel(
    const float* __restrict__ x, const float* __restrict__ beta,
    const float* __restrict__ W2,
    short* __restrict__ xb, short* __restrict__ bt,
    float* __restrict__ partials,   // [32][1024]
    float* __restrict__ wsum) {     // [1024]
    __shared__ float tls[64 * 68];
    const int bx = blockIdx.x, tid = threadIdx.x;
    if (bx < 1024) {
        const f32x4* x4 = (const f32x4*)x;
        u32x2* o2 = (u32x2*)xb;
        #pragma unroll
        for (int it = 0; it < 8; ++it) {
            const int i = (it * 1024 + bx) * 256 + tid;
            f32x4 v = x4[i];
            u32x2 p = { pkbf(v[0], v[1]), pkbf(v[2], v[3]) };
            o2[i] = p;
        }
    } else if (bx < 1536) {
        const int tile = bx - 1024, tk = tile & 31, tn = tile >> 5;
        {
            const int r = tid >> 2, c0 = (tid & 3) * 16;
            const float* src = beta + (size_t)(tk * 64 + r) * N + tn * 64 + c0;
            #pragma unroll
            for (int j = 0; j < 4; ++j)
                *(f32x4*)&tls[r * 68 + c0 + j * 4] = *(const f32x4*)(src + j * 4);
        }
        __syncthreads();
        {
            const int n = tid >> 2, k0 = (tid & 3) * 16;
            float s = 0.f;
            unsigned pk[8];
            #pragma unroll
            for (int j = 0; j < 8; ++j) {
                float a = tls[(k0 + 2 * j) * 68 + n];
                float b = tls[(k0 + 2 * j + 1) * 68 + n];
                s += fabsf(a) + fabsf(b);
                pk[j] = pkbf(a, b);
            }
            s += __shfl_xor(s, 1);
            s += __shfl_xor(s, 2);
            if ((tid & 3) == 0) partials[tk * 1024 + tn * 64 + n] = s;
            u32x4* dst = (u32x4*)(bt + (size_t)(tn * 64 + n) * K + tk * 64 + k0);
            u32x4 p0 = { pk[0], pk[1], pk[2], pk[3] };
            u32x4 p1 = { pk[4], pk[5], pk[6], pk[7] };
            dst[0] = p0; dst[1] = p1;
        }
    } else {
        const int b = bx - 1536;
        const int wv = tid >> 6, lane = tid & 63;
        const int row = b * 4 + wv;
        const f32x4* w4 = (const f32x4*)(W2 + (size_t)row * NHID);
        float acc = 0.f;
        #pragma unroll
        for (int i = 0; i < 16; ++i) {
            f32x4 v = w4[i * 64 + lane];
            acc += v[0] + v[1] + v[2] + v[3];
        }
        #pragma unroll
        for (int off = 32; off; off >>= 1) acc += __shfl_down(acc, off);
        if (lane == 0) wsum[row] = acc;
    }
}

// =================== main GEMM: 8 waves, 3-buf, counted vmcnt(3) ============
// BM=128 x BN=64, BK=64. 8 waves as 4m x 2n, wave tile 32x32 (2x2 frags, 2 kk).
// Grid 512 x 512 thr -> 2 blocks/CU = 16 waves/CU = 4/SIMD.
// LDS 72KB (3 buffers). One barrier per K-step; vmcnt-wait BEFORE barrier
// publishes staging completion to all waves (round-8-verified pattern).
// XOR swizzle: LDS slot (row, s) holds global chunk s^(row&7); reads XOR back.
constexpr int BM = 128, BN = 64, BK = 64;
constexpr int NT  = K / BK;          // 32
constexpr int ASZ = BM * BK;         // 8192 shorts (16KB)
constexpr int BSZ = BN * BK;         // 4096 shorts (8KB)

__global__ void __launch_bounds__(512, 4) gemm_kernel(
    const short* __restrict__ xb, const short* __restrict__ bt,
    const float* __restrict__ y,
    const float* __restrict__ partials, const float* __restrict__ wsum,
    const float* __restrict__ bias_lin, const float* __restrict__ bias2,
    float* __restrict__ out) {
    __shared__ __align__(16) short Al[3 * ASZ];
    __shared__ __align__(16) short Bl[3 * BSZ];

    const int tid = threadIdx.x, lane = tid & 63, w = tid >> 6;   // w: 0..7
    const int wm = w >> 1, wn = w & 1;                            // 4m x 2n
    // XCD swizzle: xcd c gets 16mb x 4nb contiguous region (512 = 8 x 64)
    const int c = blockIdx.x & 7, local = blockIdx.x >> 3;
    const int mb = ((c & 1) << 4) + (local >> 2);
    const int nb = ((c >> 1) << 2) + (local & 3);
    const int brow = mb * BM, bcol = nb * BN;

    // staging: per-lane pre-swizzled global source, linear LDS dest.
    // Each wave covers an 8-row stripe per instruction (rows w*8+srow).
    const int srow = lane >> 3;                 // 0..7
    const int schk = (lane & 7) ^ srow;         // source chunk for slot (srow, lane&7)
    // A: 2 insts, inst i covers rows i*64 + w*8 + srow
    const short* asrc = xb + (size_t)(brow + w * 8 + srow) * K + schk * 8;
    // B: 1 inst, rows w*8 + srow
    const short* bsrc = bt + (size_t)(bcol + w * 8 + srow) * K + schk * 8;
    short* Abase = &Al[w * 512];                // + i*4096 per inst
    short* Bbase = &Bl[w * 512];

    f32x4 acc[2][2];
    #pragma unroll
    for (int m = 0; m < 2; ++m)
        #pragma unroll
        for (int n = 0; n < 2; ++n) acc[m][n] = (f32x4)0.f;

    auto STAGE = [&](int buf, int t) {
        const short* a = asrc + t * BK;
        #pragma unroll
        for (int i = 0; i < 2; ++i)
            gll16(a + (size_t)i * 64 * K, Abase + buf * ASZ + i * 4096);
        gll16(bsrc + t * BK, Bbase + buf * BSZ);
    };

    // fragment LDS offsets (shorts), XOR-unswizzle on the chunk index
    const int r = lane & 15, q = lane >> 4;
    int aoff[2][2], boff[2][2];
    #pragma unroll
    for (int m = 0; m < 2; ++m)
        #pragma unroll
        for (int kk = 0; kk < 2; ++kk) {
            int row = wm * 32 + m * 16 + r;
            int ch = (kk * 4 + q) ^ (r & 7);
            aoff[m][kk] = row * 64 + ch * 8;
        }
    #pragma unroll
    for (int n = 0; n < 2; ++n)
        #pragma unroll
        for (int kk = 0; kk < 2; ++kk) {
            int row = wn * 32 + n * 16 + r;
            int ch = (kk * 4 + q) ^ (r & 7);
            boff[n][kk] = row * 64 + ch * 8;
        }

    auto COMPUTE = [&](int buf) {
        const short* A = &Al[buf * ASZ];
        const short* B = &Bl[buf * BSZ];
        #pragma unroll
        for (int kk = 0; kk < 2; ++kk) {
            bf16x8 af[2], bfr[2];
            #pragma unroll
            for (int m = 0; m < 2; ++m) af[m] = *(const bf16x8*)&A[aoff[m][kk]];
            #pragma unroll
            for (int n = 0; n < 2; ++n) bfr[n] = *(const bf16x8*)&B[boff[n][kk]];
            #pragma unroll
            for (int m = 0; m < 2; ++m)
                #pragma unroll
                for (int n = 0; n < 2; ++n)
                    acc[m][n] = __builtin_amdgcn_mfma_f32_16x16x32_bf16(
                        af[m], bfr[n], acc[m][n], 0, 0, 0);
        }
    };

    STAGE(0, 0);
    STAGE(1, 1);
    for (int t = 0; t < NT; ++t) {
        // wait own tile-t loads (3 of 6 outstanding), then barrier publishes
        // everyone's completion to the whole block.
        if (t < NT - 1) { asm volatile("s_waitcnt vmcnt(3)" ::: "memory"); }
        else            { asm volatile("s_waitcnt vmcnt(0)" ::: "memory"); }
        __builtin_amdgcn_s_barrier();
        __builtin_amdgcn_sched_barrier(0);
        if (t + 2 < NT) STAGE((t + 2) % 3, t + 2);
        COMPUTE(t % 3);
    }

    // epilogue: out = acc + cterm[col] - 0.1*bnorm[col]*y
    #pragma unroll
    for (int n = 0; n < 2; ++n) {
        const int gc = bcol + wn * 32 + n * 16 + r;
        float bsum = 0.f;
        #pragma unroll 8
        for (int tk = 0; tk < 32; ++tk) bsum += partials[tk * 1024 + gc];
        const float be = 0.1f * bsum;
        const float ct = bias_lin[gc] + bias2[gc] + (float)NHID * wsum[gc];
        #pragma unroll
        for (int m = 0; m < 2; ++m) {
            const int gr0 = brow + wm * 32 + m * 16 + q * 4;
            f32x4 v = acc[m][n];
            #pragma unroll
            for (int rr = 0; rr < 4; ++rr) {
                size_t idx = (size_t)(gr0 + rr) * N + gc;
                out[idx] = v[rr] + ct - be * y[idx];
            }
        }
    }
}

extern "C" void kernel_launch(void* const* d_in, const int* in_sizes, int n_in,
                              void* d_out, int out_size, void* d_ws, size_t ws_size,
                              hipStream_t stream) {
    const float* x        = (const float*)d_in[0];
    const float* y        = (const float*)d_in[1];
    const float* beta     = (const float*)d_in[2];
    const float* bias_lin = (const float*)d_in[3];
    const float* W2       = (const float*)d_in[5];
    const float* bias2    = (const float*)d_in[7];
    float* out = (float*)d_out;

    float* partials = (float*)d_ws;                        // [32][1024]
    float* wsum     = partials + 32 * 1024;                // [1024]
    short* xb       = (short*)(wsum + 1024);               // [M][K] bf16
    short* bts      = xb + (size_t)M * K;                  // [N][K] bf16 (beta^T)

    pre_kernel<<<1792, 256, 0, stream>>>(x, beta, W2, xb, bts, partials, wsum);
    gemm_kernel<<<512, 512, 0, stream>>>(xb, bts, y, partials, wsum,
                                         bias_lin, bias2, out);
}